// Round 18
// baseline (131.185 us; speedup 1.0000x reference)
//
#include <hip/hip_runtime.h>
#include <hip/hip_bf16.h>
#include <math.h>

// ---------------------------------------------------------------------------
// GCN 2-layer forward. Pipeline (7 dispatches, ZERO global atomics):
//   1) wprep: W1^T -> bf16 hi/lo split
//   2) histgemm: hist blocks FIRST (128 chunks x 2 ranges, 16-bit packed
//      50KB LDS histogram -> rank[i], cw[c][word]); GEMM1 blocks backfill
//      (MFMA, 3-pass split bf16) and hide hist latency
//   3) chpfx: cw -> in-place packed per-chunk exclusive prefix; count; bsum
//   4) scan2 -> rd2 = {row_start, dinv}; seeds self-loop edata
//   5) fill: direct scatter edata[rs[d]+1+pfx+rank[i]]
//   6) MEGA-B: agg1 -> h in LDS -> gemm2 -> h2 (bf16)
//   7) AGG2 (bf16 h2, 8 lanes/node) + bias + log_softmax fused
// ---------------------------------------------------------------------------

#define FIN 256
#define FH  128
#define FO  16
#define NCHUNK 128         // edge chunks
#define WPR_MAX 12544      // words per range (50176 B LDS), >= 12500

typedef unsigned int uint;
typedef unsigned short ushort;
typedef __attribute__((ext_vector_type(8))) short bf16x8;
typedef __attribute__((ext_vector_type(4))) float f32x4;

static __device__ __forceinline__ ushort f2bf(float f) {
    __hip_bfloat16 b = __float2bfloat16(f);
    return *reinterpret_cast<ushort*>(&b);
}
static __device__ __forceinline__ float bf2f(ushort u) {
    return __uint_as_float(((uint)u) << 16);
}

// W-prep: W1[256][128] fp32 -> whT/wlT [128 cols][256 k] bf16 hi/lo split.
__global__ __launch_bounds__(256) void GCN_wprep_k(const float* __restrict__ W1,
                                                   ushort* __restrict__ whT,
                                                   ushort* __restrict__ wlT) {
    int i = blockIdx.x * 256 + threadIdx.x;   // 32768
    int k = i >> 7, c = i & 127;
    float w = W1[i];
    ushort hh = f2bf(w);
    ushort hl = f2bf(w - bf2f(hh));
    whT[c * 256 + k] = hh;
    wlT[c * 256 + k] = hl;
}

// GEMM1 tile params
#define G1_BR 64
#define G1_KC 32

// blocks [0, nHist): hist (c = bid>>1, r = bid&1); [nHist, +nGemm): GEMM1.
// hist: 16-bit packed LDS histogram of chunk c's edges with dst-word in
// range r; rank[i] = LDS-atomic return; flush -> cw[c][word].
// GEMM1: h1(bf16)[N][128] = x @ W1, 3-pass split-bf16 MFMA, KC=32,
// LDS rows 64B, swizzle byte^=((r>>1)&3)<<4.
__global__ __launch_bounds__(256) void GCN_histgemm_k(
        const float* __restrict__ x, const ushort* __restrict__ whT,
        const ushort* __restrict__ wlT, ushort* __restrict__ h1,
        const int* __restrict__ edge, uint* __restrict__ cw,
        int* __restrict__ rank,
        int N, int E, int nHist, int ech, int nWords, int wpr) {
    __shared__ __align__(16) char smem[WPR_MAX * 4];   // 50176 B
    int tid = threadIdx.x;

    if ((int)blockIdx.x < nHist) {
        // ---- hist path ----
        int bid = blockIdx.x;
        int r = bid & 1;
        int c = bid >> 1;
        uint* lh = (uint*)smem;
        int w0 = r * wpr;
        int wlim = nWords - w0; if (wlim > wpr) wlim = wpr;
        for (int j = tid; j < wlim; j += 256) lh[j] = 0;
        __syncthreads();
        int base = c * ech;
        int lim = base + ech; if (lim > E) lim = E;
        for (int i = base + tid; i < lim; i += 256) {
            int d = edge[E + i];
            int wd = (d >> 1) - w0;
            if ((unsigned)wd < (unsigned)wlim) {
                int sh = (d & 1) << 4;
                uint old = atomicAdd(&lh[wd], 1u << sh);
                rank[i] = (int)((old >> sh) & 0xFFFFu);
            }
        }
        __syncthreads();
        for (int j = tid; j < wlim; j += 256)
            cw[(size_t)c * nWords + w0 + j] = lh[j];
        return;
    }

    // ---- gemm1 path ----
    ushort* xh_s = (ushort*)smem;              // 4 KiB
    ushort* xl_s = (ushort*)(smem + 4096);     // 4 KiB
    ushort* wh_s = (ushort*)(smem + 8192);     // 8 KiB
    ushort* wl_s = (ushort*)(smem + 16384);    // 8 KiB
    int row0 = (blockIdx.x - nHist) * G1_BR;
    int ln = tid & 63;
    int w  = tid >> 6;          // wave 0..3 -> col slab w*32
    int ln15 = ln & 15;
    int q16  = ln >> 4;         // k-slot 0..3

    f32x4 acc[4][2];
    #pragma unroll
    for (int mr = 0; mr < 4; mr++)
        #pragma unroll
        for (int nc = 0; nc < 2; nc++) acc[mr][nc] = (f32x4){0.f, 0.f, 0.f, 0.f};

    for (int kc = 0; kc < FIN; kc += G1_KC) {
        #pragma unroll
        for (int j = 0; j < 2; j++) {
            int u = tid + j * 256;
            int r = u >> 3, kq = u & 7;       // 8 float4 per row
            int gr = row0 + r;
            float4 v = make_float4(0.f, 0.f, 0.f, 0.f);
            if (gr < N) v = *(const float4*)&x[(size_t)gr * FIN + kc + kq * 4];
            ushort h0 = f2bf(v.x), h1v = f2bf(v.y), h2 = f2bf(v.z), h3 = f2bf(v.w);
            ushort l0 = f2bf(v.x - bf2f(h0));
            ushort l1 = f2bf(v.y - bf2f(h1v));
            ushort l2 = f2bf(v.z - bf2f(h2));
            ushort l3 = f2bf(v.w - bf2f(h3));
            uint2 hw, lw;
            hw.x = (uint)h0 | ((uint)h1v << 16);
            hw.y = (uint)h2 | ((uint)h3 << 16);
            lw.x = (uint)l0 | ((uint)l1 << 16);
            lw.y = (uint)l2 | ((uint)l3 << 16);
            int byte = (r * 64 + kq * 8) ^ (((r >> 1) & 3) << 4);
            *(uint2*)((char*)xh_s + byte) = hw;
            *(uint2*)((char*)xl_s + byte) = lw;
        }
        #pragma unroll
        for (int j = 0; j < 2; j++) {
            int u = tid + j * 256;
            int c = u >> 2, ku = u & 3;       // 4 x 16B per col
            uint4 vh = *(const uint4*)&whT[(size_t)c * 256 + kc + ku * 8];
            uint4 vl = *(const uint4*)&wlT[(size_t)c * 256 + kc + ku * 8];
            int byte = (c * 64 + ku * 16) ^ (((c >> 1) & 3) << 4);
            *(uint4*)((char*)wh_s + byte) = vh;
            *(uint4*)((char*)wl_s + byte) = vl;
        }
        __syncthreads();

        bf16x8 ah[4], al[4], bh[2], bl[2];
        #pragma unroll
        for (int mr = 0; mr < 4; mr++) {
            int r = mr * 16 + ln15;
            int byte = r * 64 + ((q16 * 16) ^ (((r >> 1) & 3) << 4));
            ah[mr] = *(const bf16x8*)((const char*)xh_s + byte);
            al[mr] = *(const bf16x8*)((const char*)xl_s + byte);
        }
        #pragma unroll
        for (int nc = 0; nc < 2; nc++) {
            int c = w * 32 + nc * 16 + ln15;
            int byte = c * 64 + ((q16 * 16) ^ (((c >> 1) & 3) << 4));
            bh[nc] = *(const bf16x8*)((const char*)wh_s + byte);
            bl[nc] = *(const bf16x8*)((const char*)wl_s + byte);
        }
        #pragma unroll
        for (int mr = 0; mr < 4; mr++)
            #pragma unroll
            for (int nc = 0; nc < 2; nc++) {
                acc[mr][nc] = __builtin_amdgcn_mfma_f32_16x16x32_bf16(
                    ah[mr], bh[nc], acc[mr][nc], 0, 0, 0);
                acc[mr][nc] = __builtin_amdgcn_mfma_f32_16x16x32_bf16(
                    al[mr], bh[nc], acc[mr][nc], 0, 0, 0);
                acc[mr][nc] = __builtin_amdgcn_mfma_f32_16x16x32_bf16(
                    ah[mr], bl[nc], acc[mr][nc], 0, 0, 0);
            }
        __syncthreads();
    }

    // epilogue: D layout col=lane&15, row=(lane>>4)*4+reg  [m89-verified]
    #pragma unroll
    for (int mr = 0; mr < 4; mr++) {
        #pragma unroll
        for (int nc = 0; nc < 2; nc++) {
            int cw2 = w * 32 + nc * 16 + ln15;
            #pragma unroll
            for (int j = 0; j < 4; j++) {
                int gr = row0 + mr * 16 + q16 * 4 + j;
                if (gr < N) h1[(size_t)gr * FH + cw2] = f2bf(acc[mr][nc][j]);
            }
        }
    }
}

// chpfx: 1 word (2 nodes)/thread. cw[c][w] -> in-place packed exclusive
// prefix over c; count[2w],count[2w+1]; bsum for two 128-thread halves.
__global__ __launch_bounds__(256) void GCN_chpfx_k(uint* __restrict__ cw,
                                                   int* __restrict__ count,
                                                   int* __restrict__ bsum,
                                                   int N, int nWords) {
    int tid = threadIdx.x;
    int w = blockIdx.x * 256 + tid;
    int local = 0;
    if (w < nWords) {
        uint re = 0, ro = 0;
        #pragma unroll 8
        for (int c = 0; c < NCHUNK; c++) {
            uint* p = &cw[(size_t)c * nWords + w];
            uint v = *p;
            *p = re | (ro << 16);
            re += v & 0xFFFFu;
            ro += v >> 16;
        }
        int d0 = 2 * w;
        if (d0 < N)     { count[d0]     = (int)re; local += (int)re + 1; }
        if (d0 + 1 < N) { count[d0 + 1] = (int)ro; local += (int)ro + 1; }
    }
    __shared__ int red[256];
    red[tid] = local;
    __syncthreads();
    for (int st = 64; st > 0; st >>= 1) {
        if ((tid & 127) < st) red[tid] += red[tid + st];
        __syncthreads();
    }
    if (tid == 0)   bsum[blockIdx.x * 2 + 0] = red[0];
    if (tid == 128) bsum[blockIdx.x * 2 + 1] = red[128];
}

// scan2: 1 node/thread. rd2[v] = {row_start[v], bits(dinv[v])}; rd2[N].x =
// total; seeds self-loop entry edata[row_start[v]] = {v, dinv^2}.
__global__ __launch_bounds__(256) void GCN_scan2_k(const int* __restrict__ count,
                                                   const int* __restrict__ bsum,
                                                   int2* __restrict__ rd2,
                                                   int2* __restrict__ edata, int N) {
    int tid = threadIdx.x;
    int b = blockIdx.x;
    int d = b * 256 + tid;
    int cnt1 = (d < N) ? count[d] + 1 : 0;

    __shared__ int red[256];
    int offp = 0;
    for (int t = tid; t < b; t += 256) offp += bsum[t];
    red[tid] = offp;
    __syncthreads();
    for (int st = 128; st > 0; st >>= 1) {
        if (tid < st) red[tid] += red[tid + st];
        __syncthreads();
    }
    int blockOff = red[0];
    __syncthreads();

    __shared__ int ssum[256];
    ssum[tid] = cnt1;
    __syncthreads();
    for (int off = 1; off < 256; off <<= 1) {
        int t = (tid >= off) ? ssum[tid - off] : 0;
        __syncthreads();
        ssum[tid] += t;
        __syncthreads();
    }
    int r = blockOff + ssum[tid] - cnt1;   // exclusive

    if (d < N) {
        float dv = rsqrtf((float)cnt1);
        rd2[d] = make_int2(r, __float_as_int(dv));
        edata[r] = make_int2(d, __float_as_int(dv * dv));  // self-loop at slot 0
    }
    if (b == gridDim.x - 1 && tid == 255) rd2[N] = make_int2(blockOff + ssum[255], 0);
}

// fill: direct scatter, no atomics.
// slot = row_start[d] + 1 + pfx(cw[c][d>>1], d&1) + rank[i],  c = i/ech.
__global__ __launch_bounds__(256) void GCN_fill_k(const int* __restrict__ edge,
                                                  const int* __restrict__ rank,
                                                  const uint* __restrict__ cw,
                                                  const int2* __restrict__ rd2,
                                                  int2* __restrict__ edata,
                                                  int E, int ech, int nWords) {
    int i = blockIdx.x * 256 + threadIdx.x;
    if (i >= E) return;
    int s = edge[i];
    int d = edge[E + i];
    int rk = rank[i];
    int c = i / ech;
    uint pw = cw[(size_t)c * nWords + (d >> 1)];
    int pfx = (int)((pw >> ((d & 1) << 4)) & 0xFFFFu);
    int2 rdd = rd2[d];
    float ds = __int_as_float(rd2[s].y);
    edata[rdd.x + 1 + pfx + rk] =
        make_int2(s, __float_as_int(ds * __int_as_float(rdd.y)));
}

// MEGA-B: agg1 (16 lanes/node, x4 unroll) -> h rows in LDS -> gemm2 fused.
// h2 written as bf16 (ushort), 32B/row.
__global__ __launch_bounds__(256) void GCN_agg1gemm2_k(
        const ushort* __restrict__ h1, const int2* __restrict__ rd2,
        const int2* __restrict__ ed, const float* __restrict__ b1,
        const float* __restrict__ W2, ushort* __restrict__ h2b, int N) {
    __shared__ float w2s[FH][FO];        // 8 KiB
    __shared__ float hs[16][FH + 4];     // 8.25 KiB
    int tid = threadIdx.x;
    #pragma unroll
    for (int j = 0; j < (FH * FO) / 256; j++) {
        int i = tid + j * 256;
        w2s[i >> 4][i & 15] = W2[i];
    }

    int node0 = blockIdx.x * 16;
    int local = tid >> 4;
    int j = tid & 15;             // 16B unit: cols 8j..8j+7
    int node = node0 + local;

    if (node < N) {
        int beg = rd2[node].x, end = rd2[node + 1].x;
        const uint4* hp = (const uint4*)h1;

        float a[8];
        #pragma unroll
        for (int t = 0; t < 8; t++) a[t] = 0.f;

        int i = beg;
        for (; i + 4 <= end; i += 4) {
            int2 e0 = ed[i + 0], e1 = ed[i + 1], e2 = ed[i + 2], e3 = ed[i + 3];
            float w0 = __int_as_float(e0.y), w1 = __int_as_float(e1.y);
            float w2 = __int_as_float(e2.y), w3 = __int_as_float(e3.y);
            uint4 g0 = hp[(size_t)e0.x * 16 + j];
            uint4 g1 = hp[(size_t)e1.x * 16 + j];
            uint4 g2 = hp[(size_t)e2.x * 16 + j];
            uint4 g3 = hp[(size_t)e3.x * 16 + j];
            #pragma unroll
            for (int q = 0; q < 4; q++) {
                uint u0 = (&g0.x)[q], u1 = (&g1.x)[q], u2 = (&g2.x)[q], u3 = (&g3.x)[q];
                a[q*2+0] += __uint_as_float(u0 << 16) * w0;
                a[q*2+1] += __uint_as_float(u0 & 0xFFFF0000u) * w0;
                a[q*2+0] += __uint_as_float(u1 << 16) * w1;
                a[q*2+1] += __uint_as_float(u1 & 0xFFFF0000u) * w1;
                a[q*2+0] += __uint_as_float(u2 << 16) * w2;
                a[q*2+1] += __uint_as_float(u2 & 0xFFFF0000u) * w2;
                a[q*2+0] += __uint_as_float(u3 << 16) * w3;
                a[q*2+1] += __uint_as_float(u3 & 0xFFFF0000u) * w3;
            }
        }
        for (; i < end; i++) {
            int2 e = ed[i];
            float w = __int_as_float(e.y);
            uint4 g = hp[(size_t)e.x * 16 + j];
            #pragma unroll
            for (int q = 0; q < 4; q++) {
                uint u = (&g.x)[q];
                a[q*2+0] += __uint_as_float(u << 16) * w;
                a[q*2+1] += __uint_as_float(u & 0xFFFF0000u) * w;
            }
        }

        const float4* bp = (const float4*)b1;
        float4 bb0 = bp[j * 2 + 0];
        float4 bb1 = bp[j * 2 + 1];
        float4 o0, o1;
        o0.x = fmaxf(a[0] + bb0.x, 0.f);
        o0.y = fmaxf(a[1] + bb0.y, 0.f);
        o0.z = fmaxf(a[2] + bb0.z, 0.f);
        o0.w = fmaxf(a[3] + bb0.w, 0.f);
        o1.x = fmaxf(a[4] + bb1.x, 0.f);
        o1.y = fmaxf(a[5] + bb1.y, 0.f);
        o1.z = fmaxf(a[6] + bb1.z, 0.f);
        o1.w = fmaxf(a[7] + bb1.w, 0.f);
        *(float4*)&hs[local][j * 8 + 0] = o0;
        *(float4*)&hs[local][j * 8 + 4] = o1;
    }
    __syncthreads();

    float acc = 0.f;
    #pragma unroll 8
    for (int k = 0; k < FH; k++) acc += hs[local][k] * w2s[k][j];
    if (node < N) h2b[(size_t)node * FO + j] = f2bf(acc);
}

// AGG2 (bf16 h2) + bias + log_softmax. 8 lanes/node, 2 cols/lane, x4 unroll.
__global__ __launch_bounds__(256) void GCN_agg2_k(const ushort* __restrict__ h2b,
                                                  const int2* __restrict__ rd2,
                                                  const int2* __restrict__ ed,
                                                  const float* __restrict__ b2,
                                                  float* __restrict__ out, int N) {
    int tid = threadIdx.x;
    int node = blockIdx.x * 32 + (tid >> 3);
    if (node >= N) return;
    int f2 = tid & 7;                        // cols 2*f2, 2*f2+1
    int beg = rd2[node].x, end = rd2[node + 1].x;
    const uint* hp = (const uint*)h2b;       // row = 8 uints (16 bf16)
    float a0 = 0.f, a1 = 0.f;
    int i = beg;
    for (; i + 4 <= end; i += 4) {
        int2 e0 = ed[i + 0], e1 = ed[i + 1], e2 = ed[i + 2], e3 = ed[i + 3];
        uint u0 = hp[(size_t)e0.x * 8 + f2];
        uint u1 = hp[(size_t)e1.x * 8 + f2];
        uint u2 = hp[(size_t)e2.x * 8 + f2];
        uint u3 = hp[(size_t)e3.x * 8 + f2];
        float w0 = __int_as_float(e0.y), w1 = __int_as_float(e1.y);
        float w2 = __int_as_float(e2.y), w3 = __int_as_float(e3.y);
        a0 += __uint_as_float(u0 << 16) * w0 + __uint_as_float(u1 << 16) * w1
            + __uint_as_float(u2 << 16) * w2 + __uint_as_float(u3 << 16) * w3;
        a1 += __uint_as_float(u0 & 0xFFFF0000u) * w0 + __uint_as_float(u1 & 0xFFFF0000u) * w1
            + __uint_as_float(u2 & 0xFFFF0000u) * w2 + __uint_as_float(u3 & 0xFFFF0000u) * w3;
    }
    for (; i < end; i++) {
        int2 e = ed[i];
        uint u = hp[(size_t)e.x * 8 + f2];
        float w = __int_as_float(e.y);
        a0 += __uint_as_float(u << 16) * w;
        a1 += __uint_as_float(u & 0xFFFF0000u) * w;
    }
    float2 bb = ((const float2*)b2)[f2];
    float v0 = a0 + bb.x;
    float v1 = a1 + bb.y;
    float mx = fmaxf(v0, v1);
    #pragma unroll
    for (int m = 4; m >= 1; m >>= 1) mx = fmaxf(mx, __shfl_xor(mx, m, 8));
    float s = expf(v0 - mx) + expf(v1 - mx);
    #pragma unroll
    for (int m = 4; m >= 1; m >>= 1) s += __shfl_xor(s, m, 8);
    float ls = logf(s);
    float2 o = make_float2(v0 - mx - ls, v1 - mx - ls);
    ((float2*)out)[(size_t)node * 8 + f2] = o;
}

extern "C" void kernel_launch(void* const* d_in, const int* in_sizes, int n_in,
                              void* d_out, int out_size, void* d_ws, size_t ws_size,
                              hipStream_t stream) {
    (void)n_in; (void)out_size; (void)ws_size;
    const float* x  = (const float*)d_in[0];
    const int*   edp = (const int*)d_in[1];
    const float* W1 = (const float*)d_in[2];
    const float* b1 = (const float*)d_in[3];
    const float* W2 = (const float*)d_in[4];
    const float* b2 = (const float*)d_in[5];
    float* out = (float*)d_out;

    int N = in_sizes[0] / FIN;   // 50000
    int E = in_sizes[1] / 2;     // 800000
    int M = E + N;
    int nWords = (N + 1) / 2;                // 25000
    int wpr = (nWords + 1) / 2;              // 12500 (<= WPR_MAX)
    int ech = (E + NCHUNK - 1) / NCHUNK;     // 6250
    int nScanBlocks = (N + 255) / 256;       // 196
    int nChpfx = (nWords + 255) / 256;       // 98  (bsum entries = 196)

    char* p = (char*)d_ws;
    auto take = [&](size_t bytes) -> char* {
        char* r = p;
        p += (bytes + 255) & ~(size_t)255;
        return r;
    };
    int*    count  = (int*)take((size_t)N * 4);
    int*    rank   = (int*)take((size_t)E * 4);
    uint*   cw     = (uint*)take((size_t)NCHUNK * nWords * 4);   // 12.8 MB
    int2*   rd2    = (int2*)take((size_t)(N + 1) * 8);
    int*    bsum   = (int*)take((size_t)(2 * nChpfx) * 4);
    int2*   edata  = (int2*)take((size_t)M * 8);
    ushort* whT    = (ushort*)take((size_t)FH * FIN * 2);
    ushort* wlT    = (ushort*)take((size_t)FH * FIN * 2);
    ushort* h1     = (ushort*)take((size_t)N * FH * 2);
    ushort* h2b    = (ushort*)take((size_t)N * FO * 2);

    int eBlocks = (E + 255) / 256;            // 3125
    int nGemm   = (N + G1_BR - 1) / G1_BR;    // 782
    int nHist   = 2 * NCHUNK;                 // 256

    GCN_wprep_k<<<(FIN * FH) / 256, 256, 0, stream>>>(W1, whT, wlT);
    GCN_histgemm_k<<<nHist + nGemm, 256, 0, stream>>>(
        x, whT, wlT, h1, edp, cw, rank, N, E, nHist, ech, nWords, wpr);
    GCN_chpfx_k<<<nChpfx, 256, 0, stream>>>(cw, count, bsum, N, nWords);
    GCN_scan2_k<<<nScanBlocks, 256, 0, stream>>>(count, bsum, rd2, edata, N);
    GCN_fill_k<<<eBlocks, 256, 0, stream>>>(edp, rank, cw, rd2, edata, E, ech, nWords);
    GCN_agg1gemm2_k<<<(N + 15) / 16, 256, 0, stream>>>(h1, rd2, edata, b1, W2, h2b, N);
    GCN_agg2_k<<<(N + 31) / 32, 256, 0, stream>>>(h2b, rd2, edata, b2, out, N);
}

// Round 19
// 116.271 us; speedup vs baseline: 1.1283x; 1.1283x over previous
//
#include <hip/hip_runtime.h>
#include <hip/hip_bf16.h>
#include <math.h>

// ---------------------------------------------------------------------------
// GCN 2-layer forward. Pipeline (7 dispatches, ZERO global atomics):
//   1) wprep: W1^T -> bf16 hi/lo split
//   2) histgemm: hist blocks FIRST (98 chunks x 2 halves, 8-bit packed 25KB
//      LDS histogram -> rank[i], cw[c][word]); GEMM1 blocks backfill
//      (MFMA, 3-pass split bf16). 25KB LDS union -> ~6 blocks/CU.
//   3) chpfx: cw -> in-place byte-packed per-chunk exclusive prefix;
//      count[d]; bsum (4 per block)
//   4) scan2 -> rd2 = {row_start, dinv}; seeds self-loop edata
//   5) fill: direct scatter edata[rs[d]+1+pfxByte+rank[i]], c = i>>13
//   6) MEGA-B: agg1 -> h in LDS -> gemm2 -> h2 (bf16)
//   7) AGG2 (bf16 h2, 8 lanes/node) + bias + log_softmax fused
// ---------------------------------------------------------------------------

#define FIN 256
#define FH  128
#define FO  16
#define ECH_LOG 13          // 8192 edges per chunk
#define ECH (1 << ECH_LOG)
#define NCHUNK 98           // ceil(800000 / 8192)
#define WPH 6272            // words per half (guard-padded >= 6250)

typedef unsigned int uint;
typedef unsigned short ushort;
typedef __attribute__((ext_vector_type(8))) short bf16x8;
typedef __attribute__((ext_vector_type(4))) float f32x4;

static __device__ __forceinline__ ushort f2bf(float f) {
    __hip_bfloat16 b = __float2bfloat16(f);
    return *reinterpret_cast<ushort*>(&b);
}
static __device__ __forceinline__ float bf2f(ushort u) {
    return __uint_as_float(((uint)u) << 16);
}

// W-prep: W1[256][128] fp32 -> whT/wlT [128 cols][256 k] bf16 hi/lo split.
__global__ __launch_bounds__(256) void GCN_wprep_k(const float* __restrict__ W1,
                                                   ushort* __restrict__ whT,
                                                   ushort* __restrict__ wlT) {
    int i = blockIdx.x * 256 + threadIdx.x;   // 32768
    int k = i >> 7, c = i & 127;
    float w = W1[i];
    ushort hh = f2bf(w);
    ushort hl = f2bf(w - bf2f(hh));
    whT[c * 256 + k] = hh;
    wlT[c * 256 + k] = hl;
}

// GEMM1 tile params
#define G1_BR 64
#define G1_KC 32

// blocks [0, nHist): hist (c = bid>>1, half = bid&1); [nHist, +nGemm): GEMM1.
// hist: 8-bit packed LDS histogram (4 nodes/word) of chunk c's edges whose
// dst-word falls in half; rank[i] = byte of LDS-atomic return; flush -> cw.
// GEMM1: h1(bf16)[N][128] = x @ W1, 3-pass split-bf16 MFMA, KC=32,
// LDS rows 64B, swizzle byte^=((r>>1)&3)<<4.
__global__ __launch_bounds__(256, 4) void GCN_histgemm_k(
        const float* __restrict__ x, const ushort* __restrict__ whT,
        const ushort* __restrict__ wlT, ushort* __restrict__ h1,
        const int* __restrict__ edge, uint* __restrict__ cw,
        int* __restrict__ rank,
        int N, int E, int nHist, int nWords, int wph) {
    __shared__ __align__(16) char smem[WPH * 4];   // 25088 B
    int tid = threadIdx.x;

    if ((int)blockIdx.x < nHist) {
        // ---- hist path ----
        int bid = blockIdx.x;
        int half = bid & 1;
        int c = bid >> 1;
        uint* lh = (uint*)smem;
        int w0 = half * wph;
        int wlim = nWords - w0; if (wlim > wph) wlim = wph;
        for (int j = tid; j < wlim; j += 256) lh[j] = 0;
        __syncthreads();
        int base = c << ECH_LOG;
        int lim = base + ECH; if (lim > E) lim = E;
        for (int i = base + tid; i < lim; i += 256) {
            int d = edge[E + i];
            int wd = (d >> 2) - w0;
            if ((unsigned)wd < (unsigned)wlim) {
                int sh = (d & 3) << 3;
                uint old = atomicAdd(&lh[wd], 1u << sh);
                rank[i] = (int)((old >> sh) & 0xFFu);
            }
        }
        __syncthreads();
        for (int j = tid; j < wlim; j += 256)
            cw[(size_t)c * nWords + w0 + j] = lh[j];
        return;
    }

    // ---- gemm1 path ----
    ushort* xh_s = (ushort*)smem;              // 4 KiB
    ushort* xl_s = (ushort*)(smem + 4096);     // 4 KiB
    ushort* wh_s = (ushort*)(smem + 8192);     // 8 KiB
    ushort* wl_s = (ushort*)(smem + 16384);    // 8 KiB
    int row0 = (blockIdx.x - nHist) * G1_BR;
    int ln = tid & 63;
    int w  = tid >> 6;          // wave 0..3 -> col slab w*32
    int ln15 = ln & 15;
    int q16  = ln >> 4;         // k-slot 0..3

    f32x4 acc[4][2];
    #pragma unroll
    for (int mr = 0; mr < 4; mr++)
        #pragma unroll
        for (int nc = 0; nc < 2; nc++) acc[mr][nc] = (f32x4){0.f, 0.f, 0.f, 0.f};

    for (int kc = 0; kc < FIN; kc += G1_KC) {
        #pragma unroll
        for (int j = 0; j < 2; j++) {
            int u = tid + j * 256;
            int r = u >> 3, kq = u & 7;       // 8 float4 per row
            int gr = row0 + r;
            float4 v = make_float4(0.f, 0.f, 0.f, 0.f);
            if (gr < N) v = *(const float4*)&x[(size_t)gr * FIN + kc + kq * 4];
            ushort h0 = f2bf(v.x), h1v = f2bf(v.y), h2 = f2bf(v.z), h3 = f2bf(v.w);
            ushort l0 = f2bf(v.x - bf2f(h0));
            ushort l1 = f2bf(v.y - bf2f(h1v));
            ushort l2 = f2bf(v.z - bf2f(h2));
            ushort l3 = f2bf(v.w - bf2f(h3));
            uint2 hw, lw;
            hw.x = (uint)h0 | ((uint)h1v << 16);
            hw.y = (uint)h2 | ((uint)h3 << 16);
            lw.x = (uint)l0 | ((uint)l1 << 16);
            lw.y = (uint)l2 | ((uint)l3 << 16);
            int byte = (r * 64 + kq * 8) ^ (((r >> 1) & 3) << 4);
            *(uint2*)((char*)xh_s + byte) = hw;
            *(uint2*)((char*)xl_s + byte) = lw;
        }
        #pragma unroll
        for (int j = 0; j < 2; j++) {
            int u = tid + j * 256;
            int c = u >> 2, ku = u & 3;       // 4 x 16B per col
            uint4 vh = *(const uint4*)&whT[(size_t)c * 256 + kc + ku * 8];
            uint4 vl = *(const uint4*)&wlT[(size_t)c * 256 + kc + ku * 8];
            int byte = (c * 64 + ku * 16) ^ (((c >> 1) & 3) << 4);
            *(uint4*)((char*)wh_s + byte) = vh;
            *(uint4*)((char*)wl_s + byte) = vl;
        }
        __syncthreads();

        bf16x8 ah[4], al[4], bh[2], bl[2];
        #pragma unroll
        for (int mr = 0; mr < 4; mr++) {
            int r = mr * 16 + ln15;
            int byte = r * 64 + ((q16 * 16) ^ (((r >> 1) & 3) << 4));
            ah[mr] = *(const bf16x8*)((const char*)xh_s + byte);
            al[mr] = *(const bf16x8*)((const char*)xl_s + byte);
        }
        #pragma unroll
        for (int nc = 0; nc < 2; nc++) {
            int c = w * 32 + nc * 16 + ln15;
            int byte = c * 64 + ((q16 * 16) ^ (((c >> 1) & 3) << 4));
            bh[nc] = *(const bf16x8*)((const char*)wh_s + byte);
            bl[nc] = *(const bf16x8*)((const char*)wl_s + byte);
        }
        #pragma unroll
        for (int mr = 0; mr < 4; mr++)
            #pragma unroll
            for (int nc = 0; nc < 2; nc++) {
                acc[mr][nc] = __builtin_amdgcn_mfma_f32_16x16x32_bf16(
                    ah[mr], bh[nc], acc[mr][nc], 0, 0, 0);
                acc[mr][nc] = __builtin_amdgcn_mfma_f32_16x16x32_bf16(
                    al[mr], bh[nc], acc[mr][nc], 0, 0, 0);
                acc[mr][nc] = __builtin_amdgcn_mfma_f32_16x16x32_bf16(
                    ah[mr], bl[nc], acc[mr][nc], 0, 0, 0);
            }
        __syncthreads();
    }

    // epilogue: D layout col=lane&15, row=(lane>>4)*4+reg  [m89-verified]
    #pragma unroll
    for (int mr = 0; mr < 4; mr++) {
        #pragma unroll
        for (int nc = 0; nc < 2; nc++) {
            int cw2 = w * 32 + nc * 16 + ln15;
            #pragma unroll
            for (int j = 0; j < 4; j++) {
                int gr = row0 + mr * 16 + q16 * 4 + j;
                if (gr < N) h1[(size_t)gr * FH + cw2] = f2bf(acc[mr][nc][j]);
            }
        }
    }
}

// chpfx: 1 word (4 nodes)/thread. cw[c][w] -> in-place byte-packed exclusive
// prefix over c; count[4w..4w+3]; bsum per 64-thread quarter (256 nodes).
__global__ __launch_bounds__(256) void GCN_chpfx_k(uint* __restrict__ cw,
                                                   int* __restrict__ count,
                                                   int* __restrict__ bsum,
                                                   int N, int nWords) {
    int tid = threadIdx.x;
    int w = blockIdx.x * 256 + tid;
    int local = 0;
    if (w < nWords) {
        uint s0 = 0, s1 = 0, s2 = 0, s3 = 0;
        for (int c = 0; c < NCHUNK; c++) {
            uint* p = &cw[(size_t)c * nWords + w];
            uint v = *p;
            *p = s0 | (s1 << 8) | (s2 << 16) | (s3 << 24);
            s0 += v & 0xFFu;
            s1 += (v >> 8) & 0xFFu;
            s2 += (v >> 16) & 0xFFu;
            s3 += (v >> 24) & 0xFFu;
        }
        int d0 = 4 * w;
        count[d0 + 0] = (int)s0;
        count[d0 + 1] = (int)s1;
        count[d0 + 2] = (int)s2;
        count[d0 + 3] = (int)s3;
        local = (int)(s0 + s1 + s2 + s3) + 4;
    }
    __shared__ int red[256];
    red[tid] = local;
    __syncthreads();
    for (int st = 32; st > 0; st >>= 1) {
        if ((tid & 63) < st) red[tid] += red[tid + st];
        __syncthreads();
    }
    if ((tid & 63) == 0) bsum[blockIdx.x * 4 + (tid >> 6)] = red[tid];
}

// scan2: 1 node/thread. rd2[v] = {row_start[v], bits(dinv[v])}; rd2[N].x =
// total; seeds self-loop entry edata[row_start[v]] = {v, dinv^2}.
__global__ __launch_bounds__(256) void GCN_scan2_k(const int* __restrict__ count,
                                                   const int* __restrict__ bsum,
                                                   int2* __restrict__ rd2,
                                                   int2* __restrict__ edata, int N) {
    int tid = threadIdx.x;
    int b = blockIdx.x;
    int d = b * 256 + tid;
    int cnt1 = (d < N) ? count[d] + 1 : 0;

    __shared__ int red[256];
    int offp = 0;
    for (int t = tid; t < b; t += 256) offp += bsum[t];
    red[tid] = offp;
    __syncthreads();
    for (int st = 128; st > 0; st >>= 1) {
        if (tid < st) red[tid] += red[tid + st];
        __syncthreads();
    }
    int blockOff = red[0];
    __syncthreads();

    __shared__ int ssum[256];
    ssum[tid] = cnt1;
    __syncthreads();
    for (int off = 1; off < 256; off <<= 1) {
        int t = (tid >= off) ? ssum[tid - off] : 0;
        __syncthreads();
        ssum[tid] += t;
        __syncthreads();
    }
    int r = blockOff + ssum[tid] - cnt1;   // exclusive

    if (d < N) {
        float dv = rsqrtf((float)cnt1);
        rd2[d] = make_int2(r, __float_as_int(dv));
        edata[r] = make_int2(d, __float_as_int(dv * dv));  // self-loop at slot 0
    }
    if (b == gridDim.x - 1 && tid == 255) rd2[N] = make_int2(blockOff + ssum[255], 0);
}

// fill: direct scatter, no atomics.
// slot = row_start[d] + 1 + byte(cw[c][d>>2], d&3) + rank[i],  c = i>>13.
__global__ __launch_bounds__(256) void GCN_fill_k(const int* __restrict__ edge,
                                                  const int* __restrict__ rank,
                                                  const uint* __restrict__ cw,
                                                  const int2* __restrict__ rd2,
                                                  int2* __restrict__ edata,
                                                  int E, int nWords) {
    int i = blockIdx.x * 256 + threadIdx.x;
    if (i >= E) return;
    int s = edge[i];
    int d = edge[E + i];
    int rk = rank[i];
    int c = i >> ECH_LOG;
    uint pw = cw[(size_t)c * nWords + (d >> 2)];
    int pfx = (int)((pw >> ((d & 3) << 3)) & 0xFFu);
    int2 rdd = rd2[d];
    float ds = __int_as_float(rd2[s].y);
    edata[rdd.x + 1 + pfx + rk] =
        make_int2(s, __float_as_int(ds * __int_as_float(rdd.y)));
}

// MEGA-B: agg1 (16 lanes/node, x4 unroll) -> h rows in LDS -> gemm2 fused.
// h2 written as bf16 (ushort), 32B/row.
__global__ __launch_bounds__(256) void GCN_agg1gemm2_k(
        const ushort* __restrict__ h1, const int2* __restrict__ rd2,
        const int2* __restrict__ ed, const float* __restrict__ b1,
        const float* __restrict__ W2, ushort* __restrict__ h2b, int N) {
    __shared__ float w2s[FH][FO];        // 8 KiB
    __shared__ float hs[16][FH + 4];     // 8.25 KiB
    int tid = threadIdx.x;
    #pragma unroll
    for (int j = 0; j < (FH * FO) / 256; j++) {
        int i = tid + j * 256;
        w2s[i >> 4][i & 15] = W2[i];
    }

    int node0 = blockIdx.x * 16;
    int local = tid >> 4;
    int j = tid & 15;             // 16B unit: cols 8j..8j+7
    int node = node0 + local;

    if (node < N) {
        int beg = rd2[node].x, end = rd2[node + 1].x;
        const uint4* hp = (const uint4*)h1;

        float a[8];
        #pragma unroll
        for (int t = 0; t < 8; t++) a[t] = 0.f;

        int i = beg;
        for (; i + 4 <= end; i += 4) {
            int2 e0 = ed[i + 0], e1 = ed[i + 1], e2 = ed[i + 2], e3 = ed[i + 3];
            float w0 = __int_as_float(e0.y), w1 = __int_as_float(e1.y);
            float w2 = __int_as_float(e2.y), w3 = __int_as_float(e3.y);
            uint4 g0 = hp[(size_t)e0.x * 16 + j];
            uint4 g1 = hp[(size_t)e1.x * 16 + j];
            uint4 g2 = hp[(size_t)e2.x * 16 + j];
            uint4 g3 = hp[(size_t)e3.x * 16 + j];
            #pragma unroll
            for (int q = 0; q < 4; q++) {
                uint u0 = (&g0.x)[q], u1 = (&g1.x)[q], u2 = (&g2.x)[q], u3 = (&g3.x)[q];
                a[q*2+0] += __uint_as_float(u0 << 16) * w0;
                a[q*2+1] += __uint_as_float(u0 & 0xFFFF0000u) * w0;
                a[q*2+0] += __uint_as_float(u1 << 16) * w1;
                a[q*2+1] += __uint_as_float(u1 & 0xFFFF0000u) * w1;
                a[q*2+0] += __uint_as_float(u2 << 16) * w2;
                a[q*2+1] += __uint_as_float(u2 & 0xFFFF0000u) * w2;
                a[q*2+0] += __uint_as_float(u3 << 16) * w3;
                a[q*2+1] += __uint_as_float(u3 & 0xFFFF0000u) * w3;
            }
        }
        for (; i < end; i++) {
            int2 e = ed[i];
            float w = __int_as_float(e.y);
            uint4 g = hp[(size_t)e.x * 16 + j];
            #pragma unroll
            for (int q = 0; q < 4; q++) {
                uint u = (&g.x)[q];
                a[q*2+0] += __uint_as_float(u << 16) * w;
                a[q*2+1] += __uint_as_float(u & 0xFFFF0000u) * w;
            }
        }

        const float4* bp = (const float4*)b1;
        float4 bb0 = bp[j * 2 + 0];
        float4 bb1 = bp[j * 2 + 1];
        float4 o0, o1;
        o0.x = fmaxf(a[0] + bb0.x, 0.f);
        o0.y = fmaxf(a[1] + bb0.y, 0.f);
        o0.z = fmaxf(a[2] + bb0.z, 0.f);
        o0.w = fmaxf(a[3] + bb0.w, 0.f);
        o1.x = fmaxf(a[4] + bb1.x, 0.f);
        o1.y = fmaxf(a[5] + bb1.y, 0.f);
        o1.z = fmaxf(a[6] + bb1.z, 0.f);
        o1.w = fmaxf(a[7] + bb1.w, 0.f);
        *(float4*)&hs[local][j * 8 + 0] = o0;
        *(float4*)&hs[local][j * 8 + 4] = o1;
    }
    __syncthreads();

    float acc = 0.f;
    #pragma unroll 8
    for (int k = 0; k < FH; k++) acc += hs[local][k] * w2s[k][j];
    if (node < N) h2b[(size_t)node * FO + j] = f2bf(acc);
}

// AGG2 (bf16 h2) + bias + log_softmax. 8 lanes/node, 2 cols/lane, x4 unroll.
__global__ __launch_bounds__(256) void GCN_agg2_k(const ushort* __restrict__ h2b,
                                                  const int2* __restrict__ rd2,
                                                  const int2* __restrict__ ed,
                                                  const float* __restrict__ b2,
                                                  float* __restrict__ out, int N) {
    int tid = threadIdx.x;
    int node = blockIdx.x * 32 + (tid >> 3);
    if (node >= N) return;
    int f2 = tid & 7;                        // cols 2*f2, 2*f2+1
    int beg = rd2[node].x, end = rd2[node + 1].x;
    const uint* hp = (const uint*)h2b;       // row = 8 uints (16 bf16)
    float a0 = 0.f, a1 = 0.f;
    int i = beg;
    for (; i + 4 <= end; i += 4) {
        int2 e0 = ed[i + 0], e1 = ed[i + 1], e2 = ed[i + 2], e3 = ed[i + 3];
        uint u0 = hp[(size_t)e0.x * 8 + f2];
        uint u1 = hp[(size_t)e1.x * 8 + f2];
        uint u2 = hp[(size_t)e2.x * 8 + f2];
        uint u3 = hp[(size_t)e3.x * 8 + f2];
        float w0 = __int_as_float(e0.y), w1 = __int_as_float(e1.y);
        float w2 = __int_as_float(e2.y), w3 = __int_as_float(e3.y);
        a0 += __uint_as_float(u0 << 16) * w0 + __uint_as_float(u1 << 16) * w1
            + __uint_as_float(u2 << 16) * w2 + __uint_as_float(u3 << 16) * w3;
        a1 += __uint_as_float(u0 & 0xFFFF0000u) * w0 + __uint_as_float(u1 & 0xFFFF0000u) * w1
            + __uint_as_float(u2 & 0xFFFF0000u) * w2 + __uint_as_float(u3 & 0xFFFF0000u) * w3;
    }
    for (; i < end; i++) {
        int2 e = ed[i];
        uint u = hp[(size_t)e.x * 8 + f2];
        float w = __int_as_float(e.y);
        a0 += __uint_as_float(u << 16) * w;
        a1 += __uint_as_float(u & 0xFFFF0000u) * w;
    }
    float2 bb = ((const float2*)b2)[f2];
    float v0 = a0 + bb.x;
    float v1 = a1 + bb.y;
    float mx = fmaxf(v0, v1);
    #pragma unroll
    for (int m = 4; m >= 1; m >>= 1) mx = fmaxf(mx, __shfl_xor(mx, m, 8));
    float s = expf(v0 - mx) + expf(v1 - mx);
    #pragma unroll
    for (int m = 4; m >= 1; m >>= 1) s += __shfl_xor(s, m, 8);
    float ls = logf(s);
    float2 o = make_float2(v0 - mx - ls, v1 - mx - ls);
    ((float2*)out)[(size_t)node * 8 + f2] = o;
}

extern "C" void kernel_launch(void* const* d_in, const int* in_sizes, int n_in,
                              void* d_out, int out_size, void* d_ws, size_t ws_size,
                              hipStream_t stream) {
    (void)n_in; (void)out_size; (void)ws_size;
    const float* x  = (const float*)d_in[0];
    const int*   edp = (const int*)d_in[1];
    const float* W1 = (const float*)d_in[2];
    const float* b1 = (const float*)d_in[3];
    const float* W2 = (const float*)d_in[4];
    const float* b2 = (const float*)d_in[5];
    float* out = (float*)d_out;

    int N = in_sizes[0] / FIN;   // 50000
    int E = in_sizes[1] / 2;     // 800000
    int M = E + N;
    int nWords = (N + 3) / 4;                // 12500 (4 nodes/word)
    int wph = (nWords + 1) / 2;              // 6250 (<= WPH)
    int nScanBlocks = (N + 255) / 256;       // 196
    int nChpfx = (nWords + 255) / 256;       // 49  (bsum entries = 196)

    char* p = (char*)d_ws;
    auto take = [&](size_t bytes) -> char* {
        char* r = p;
        p += (bytes + 255) & ~(size_t)255;
        return r;
    };
    int*    count  = (int*)take((size_t)N * 4);
    int*    rank   = (int*)take((size_t)E * 4);
    uint*   cw     = (uint*)take((size_t)NCHUNK * nWords * 4);   // 4.9 MB
    int2*   rd2    = (int2*)take((size_t)(N + 1) * 8);
    int*    bsum   = (int*)take((size_t)(4 * nChpfx) * 4);
    int2*   edata  = (int2*)take((size_t)M * 8);
    ushort* whT    = (ushort*)take((size_t)FH * FIN * 2);
    ushort* wlT    = (ushort*)take((size_t)FH * FIN * 2);
    ushort* h1     = (ushort*)take((size_t)N * FH * 2);
    ushort* h2b    = (ushort*)take((size_t)N * FO * 2);

    int eBlocks = (E + 255) / 256;            // 3125
    int nGemm   = (N + G1_BR - 1) / G1_BR;    // 782
    int nHist   = 2 * NCHUNK;                 // 196

    GCN_wprep_k<<<(FIN * FH) / 256, 256, 0, stream>>>(W1, whT, wlT);
    GCN_histgemm_k<<<nHist + nGemm, 256, 0, stream>>>(
        x, whT, wlT, h1, edp, cw, rank, N, E, nHist, nWords, wph);
    GCN_chpfx_k<<<nChpfx, 256, 0, stream>>>(cw, count, bsum, N, nWords);
    GCN_scan2_k<<<nScanBlocks, 256, 0, stream>>>(count, bsum, rd2, edata, N);
    GCN_fill_k<<<eBlocks, 256, 0, stream>>>(edp, rank, cw, rd2, edata, E, nWords);
    GCN_agg1gemm2_k<<<(N + 15) / 16, 256, 0, stream>>>(h1, rd2, edata, b1, W2, h2b, N);
    GCN_agg2_k<<<(N + 31) / 32, 256, 0, stream>>>(h2b, rd2, edata, b2, out, N);
}

// Round 20
// 113.352 us; speedup vs baseline: 1.1573x; 1.0258x over previous
//
#include <hip/hip_runtime.h>
#include <hip/hip_bf16.h>
#include <math.h>

// ---------------------------------------------------------------------------
// GCN 2-layer forward. Pipeline (7 dispatches, ZERO global atomics):
//   1) wprep: W1^T -> bf16 hi/lo split
//   2) histgemm: hist blocks FIRST (98 chunks x 2 halves, 8-bit packed 25KB
//      LDS histogram -> rank[i], cw[c][word]); GEMM1 blocks backfill
//      (MFMA, 2-pass: bf16(x)*(Wh+Wl), fp32 accum)
//   3) chpfx: PARALLEL packed per-chunk prefix (196 blocks, 64 words x
//      4 chunk-groups, LDS combine); count[d]; bsum
//   4) scan2 -> rd2 = {row_start, dinv}; seeds self-loop edata
//   5) fill: direct scatter edata[rs[d]+1+pfxByte+rank[i]], c = i>>13
//   6) MEGA-B: agg1 (x8-deep gather MLP) -> h in LDS -> gemm2 -> h2 (bf16)
//   7) AGG2 (bf16 h2, 8 lanes/node, x8 unroll) + bias + log_softmax fused
// ---------------------------------------------------------------------------

#define FIN 256
#define FH  128
#define FO  16
#define ECH_LOG 13          // 8192 edges per chunk
#define ECH (1 << ECH_LOG)
#define NCHUNK 98           // ceil(800000 / 8192)
#define WPH 6272            // words per half (guard-padded >= 6250)

typedef unsigned int uint;
typedef unsigned short ushort;
typedef __attribute__((ext_vector_type(8))) short bf16x8;
typedef __attribute__((ext_vector_type(4))) float f32x4;

static __device__ __forceinline__ ushort f2bf(float f) {
    __hip_bfloat16 b = __float2bfloat16(f);
    return *reinterpret_cast<ushort*>(&b);
}
static __device__ __forceinline__ float bf2f(ushort u) {
    return __uint_as_float(((uint)u) << 16);
}

// W-prep: W1[256][128] fp32 -> whT/wlT [128 cols][256 k] bf16 hi/lo split.
__global__ __launch_bounds__(256) void GCN_wprep_k(const float* __restrict__ W1,
                                                   ushort* __restrict__ whT,
                                                   ushort* __restrict__ wlT) {
    int i = blockIdx.x * 256 + threadIdx.x;   // 32768
    int k = i >> 7, c = i & 127;
    float w = W1[i];
    ushort hh = f2bf(w);
    ushort hl = f2bf(w - bf2f(hh));
    whT[c * 256 + k] = hh;
    wlT[c * 256 + k] = hl;
}

// GEMM1 tile params
#define G1_BR 64
#define G1_KC 32

// blocks [0, nHist): hist (c = bid>>1, half = bid&1); [nHist, +nGemm): GEMM1.
// hist: 8-bit packed LDS histogram (4 nodes/word) of chunk c's edges whose
// dst-word falls in half; rank[i] = byte of LDS-atomic return; flush -> cw.
// GEMM1: h1(bf16)[N][128] = bf16(x) @ (Wh + Wl), 2-pass MFMA, KC=32.
__global__ __launch_bounds__(256, 4) void GCN_histgemm_k(
        const float* __restrict__ x, const ushort* __restrict__ whT,
        const ushort* __restrict__ wlT, ushort* __restrict__ h1,
        const int* __restrict__ edge, uint* __restrict__ cw,
        int* __restrict__ rank,
        int N, int E, int nHist, int nWords, int wph) {
    __shared__ __align__(16) char smem[WPH * 4];   // 25088 B
    int tid = threadIdx.x;

    if ((int)blockIdx.x < nHist) {
        // ---- hist path ----
        int bid = blockIdx.x;
        int half = bid & 1;
        int c = bid >> 1;
        uint* lh = (uint*)smem;
        int w0 = half * wph;
        int wlim = nWords - w0; if (wlim > wph) wlim = wph;
        for (int j = tid; j < wlim; j += 256) lh[j] = 0;
        __syncthreads();
        int base = c << ECH_LOG;
        int lim = base + ECH; if (lim > E) lim = E;
        for (int i = base + tid; i < lim; i += 256) {
            int d = edge[E + i];
            int wd = (d >> 2) - w0;
            if ((unsigned)wd < (unsigned)wlim) {
                int sh = (d & 3) << 3;
                uint old = atomicAdd(&lh[wd], 1u << sh);
                rank[i] = (int)((old >> sh) & 0xFFu);
            }
        }
        __syncthreads();
        for (int j = tid; j < wlim; j += 256)
            cw[(size_t)c * nWords + w0 + j] = lh[j];
        return;
    }

    // ---- gemm1 path (2-pass: xh*(wh+wl)) ----
    ushort* xh_s = (ushort*)smem;              // 4 KiB
    ushort* wh_s = (ushort*)(smem + 4096);     // 8 KiB
    ushort* wl_s = (ushort*)(smem + 12288);    // 8 KiB
    int row0 = (blockIdx.x - nHist) * G1_BR;
    int ln = tid & 63;
    int w  = tid >> 6;          // wave 0..3 -> col slab w*32
    int ln15 = ln & 15;
    int q16  = ln >> 4;         // k-slot 0..3

    f32x4 acc[4][2];
    #pragma unroll
    for (int mr = 0; mr < 4; mr++)
        #pragma unroll
        for (int nc = 0; nc < 2; nc++) acc[mr][nc] = (f32x4){0.f, 0.f, 0.f, 0.f};

    for (int kc = 0; kc < FIN; kc += G1_KC) {
        #pragma unroll
        for (int j = 0; j < 2; j++) {
            int u = tid + j * 256;
            int r = u >> 3, kq = u & 7;       // 8 float4 per row
            int gr = row0 + r;
            float4 v = make_float4(0.f, 0.f, 0.f, 0.f);
            if (gr < N) v = *(const float4*)&x[(size_t)gr * FIN + kc + kq * 4];
            uint2 hw;
            hw.x = (uint)f2bf(v.x) | ((uint)f2bf(v.y) << 16);
            hw.y = (uint)f2bf(v.z) | ((uint)f2bf(v.w) << 16);
            int byte = (r * 64 + kq * 8) ^ (((r >> 1) & 3) << 4);
            *(uint2*)((char*)xh_s + byte) = hw;
        }
        #pragma unroll
        for (int j = 0; j < 2; j++) {
            int u = tid + j * 256;
            int c = u >> 2, ku = u & 3;       // 4 x 16B per col
            uint4 vh = *(const uint4*)&whT[(size_t)c * 256 + kc + ku * 8];
            uint4 vl = *(const uint4*)&wlT[(size_t)c * 256 + kc + ku * 8];
            int byte = (c * 64 + ku * 16) ^ (((c >> 1) & 3) << 4);
            *(uint4*)((char*)wh_s + byte) = vh;
            *(uint4*)((char*)wl_s + byte) = vl;
        }
        __syncthreads();

        bf16x8 ah[4], bh[2], bl[2];
        #pragma unroll
        for (int mr = 0; mr < 4; mr++) {
            int r = mr * 16 + ln15;
            int byte = r * 64 + ((q16 * 16) ^ (((r >> 1) & 3) << 4));
            ah[mr] = *(const bf16x8*)((const char*)xh_s + byte);
        }
        #pragma unroll
        for (int nc = 0; nc < 2; nc++) {
            int c = w * 32 + nc * 16 + ln15;
            int byte = c * 64 + ((q16 * 16) ^ (((c >> 1) & 3) << 4));
            bh[nc] = *(const bf16x8*)((const char*)wh_s + byte);
            bl[nc] = *(const bf16x8*)((const char*)wl_s + byte);
        }
        #pragma unroll
        for (int mr = 0; mr < 4; mr++)
            #pragma unroll
            for (int nc = 0; nc < 2; nc++) {
                acc[mr][nc] = __builtin_amdgcn_mfma_f32_16x16x32_bf16(
                    ah[mr], bh[nc], acc[mr][nc], 0, 0, 0);
                acc[mr][nc] = __builtin_amdgcn_mfma_f32_16x16x32_bf16(
                    ah[mr], bl[nc], acc[mr][nc], 0, 0, 0);
            }
        __syncthreads();
    }

    // epilogue: D layout col=lane&15, row=(lane>>4)*4+reg  [m89-verified]
    #pragma unroll
    for (int mr = 0; mr < 4; mr++) {
        #pragma unroll
        for (int nc = 0; nc < 2; nc++) {
            int cw2 = w * 32 + nc * 16 + ln15;
            #pragma unroll
            for (int j = 0; j < 4; j++) {
                int gr = row0 + mr * 16 + q16 * 4 + j;
                if (gr < N) h1[(size_t)gr * FH + cw2] = f2bf(acc[mr][nc][j]);
            }
        }
    }
}

// chpfx (parallel): block = 64 words x 4 chunk-groups. Per-group partial
// byte-lane sums -> LDS -> per-group base -> in-place packed prefix rewrite.
// count[4w..4w+3] and per-block bsum (block b == scan2 block b: 256 nodes).
__global__ __launch_bounds__(256) void GCN_chpfx_k(uint* __restrict__ cw,
                                                   int* __restrict__ count,
                                                   int* __restrict__ bsum,
                                                   int N, int nWords) {
    __shared__ int part[4][64][4];   // [group][word][lane] = 4 KiB
    __shared__ int red[64];
    int tid = threadIdx.x;
    int wl = tid & 63, g = tid >> 6;
    int w = blockIdx.x * 64 + wl;
    int c0 = g * 25;
    int c1 = c0 + 25; if (c1 > NCHUNK) c1 = NCHUNK;

    int s0 = 0, s1 = 0, s2 = 0, s3 = 0;
    if (w < nWords) {
        for (int c = c0; c < c1; c++) {
            uint v = cw[(size_t)c * nWords + w];
            s0 += (int)(v & 0xFFu);
            s1 += (int)((v >> 8) & 0xFFu);
            s2 += (int)((v >> 16) & 0xFFu);
            s3 += (int)((v >> 24) & 0xFFu);
        }
    }
    part[g][wl][0] = s0; part[g][wl][1] = s1;
    part[g][wl][2] = s2; part[g][wl][3] = s3;
    __syncthreads();

    int b0 = 0, b1 = 0, b2 = 0, b3 = 0;
    for (int gg = 0; gg < g; gg++) {
        b0 += part[gg][wl][0]; b1 += part[gg][wl][1];
        b2 += part[gg][wl][2]; b3 += part[gg][wl][3];
    }
    if (w < nWords) {
        uint r0 = (uint)b0, r1 = (uint)b1, r2 = (uint)b2, r3 = (uint)b3;
        for (int c = c0; c < c1; c++) {
            uint* p = &cw[(size_t)c * nWords + w];
            uint v = *p;
            *p = (r0 & 0xFFu) | ((r1 & 0xFFu) << 8) | ((r2 & 0xFFu) << 16) | ((r3 & 0xFFu) << 24);
            r0 += v & 0xFFu;
            r1 += (v >> 8) & 0xFFu;
            r2 += (v >> 16) & 0xFFu;
            r3 += (v >> 24) & 0xFFu;
        }
    }
    int local = 0;
    if (g == 3 && w < nWords) {
        int t0 = b0 + s0, t1 = b1 + s1, t2 = b2 + s2, t3 = b3 + s3;
        int d0 = 4 * w;
        if (d0 + 0 < N) count[d0 + 0] = t0;
        if (d0 + 1 < N) count[d0 + 1] = t1;
        if (d0 + 2 < N) count[d0 + 2] = t2;
        if (d0 + 3 < N) count[d0 + 3] = t3;
        local = t0 + t1 + t2 + t3 + 4;
    }
    if (g == 3) red[wl] = local;
    __syncthreads();
    if (tid < 32) { red[tid] += red[tid + 32]; }
    __syncthreads();
    if (tid < 16) { red[tid] += red[tid + 16]; }
    __syncthreads();
    if (tid < 8) { red[tid] += red[tid + 8]; }
    __syncthreads();
    if (tid < 4) { red[tid] += red[tid + 4]; }
    __syncthreads();
    if (tid == 0) bsum[blockIdx.x] = red[0] + red[1] + red[2] + red[3];
}

// scan2: 1 node/thread. rd2[v] = {row_start[v], bits(dinv[v])}; rd2[N].x =
// total; seeds self-loop entry edata[row_start[v]] = {v, dinv^2}.
__global__ __launch_bounds__(256) void GCN_scan2_k(const int* __restrict__ count,
                                                   const int* __restrict__ bsum,
                                                   int2* __restrict__ rd2,
                                                   int2* __restrict__ edata, int N) {
    int tid = threadIdx.x;
    int b = blockIdx.x;
    int d = b * 256 + tid;
    int cnt1 = (d < N) ? count[d] + 1 : 0;

    __shared__ int red[256];
    int offp = 0;
    for (int t = tid; t < b; t += 256) offp += bsum[t];
    red[tid] = offp;
    __syncthreads();
    for (int st = 128; st > 0; st >>= 1) {
        if (tid < st) red[tid] += red[tid + st];
        __syncthreads();
    }
    int blockOff = red[0];
    __syncthreads();

    __shared__ int ssum[256];
    ssum[tid] = cnt1;
    __syncthreads();
    for (int off = 1; off < 256; off <<= 1) {
        int t = (tid >= off) ? ssum[tid - off] : 0;
        __syncthreads();
        ssum[tid] += t;
        __syncthreads();
    }
    int r = blockOff + ssum[tid] - cnt1;   // exclusive

    if (d < N) {
        float dv = rsqrtf((float)cnt1);
        rd2[d] = make_int2(r, __float_as_int(dv));
        edata[r] = make_int2(d, __float_as_int(dv * dv));  // self-loop at slot 0
    }
    if (b == gridDim.x - 1 && tid == 255) rd2[N] = make_int2(blockOff + ssum[255], 0);
}

// fill: direct scatter, no atomics.
// slot = row_start[d] + 1 + byte(cw[c][d>>2], d&3) + rank[i],  c = i>>13.
__global__ __launch_bounds__(256) void GCN_fill_k(const int* __restrict__ edge,
                                                  const int* __restrict__ rank,
                                                  const uint* __restrict__ cw,
                                                  const int2* __restrict__ rd2,
                                                  int2* __restrict__ edata,
                                                  int E, int nWords) {
    int i = blockIdx.x * 256 + threadIdx.x;
    if (i >= E) return;
    int s = edge[i];
    int d = edge[E + i];
    int rk = rank[i];
    int c = i >> ECH_LOG;
    uint pw = cw[(size_t)c * nWords + (d >> 2)];
    int pfx = (int)((pw >> ((d & 3) << 3)) & 0xFFu);
    int2 rdd = rd2[d];
    float ds = __int_as_float(rd2[s].y);
    edata[rdd.x + 1 + pfx + rk] =
        make_int2(s, __float_as_int(ds * __int_as_float(rdd.y)));
}

// MEGA-B: agg1 (16 lanes/node, x8-deep gather MLP) -> h in LDS -> gemm2.
// h2 written as bf16 (ushort), 32B/row.
__global__ __launch_bounds__(256) void GCN_agg1gemm2_k(
        const ushort* __restrict__ h1, const int2* __restrict__ rd2,
        const int2* __restrict__ ed, const float* __restrict__ b1,
        const float* __restrict__ W2, ushort* __restrict__ h2b, int N) {
    __shared__ float w2s[FH][FO];        // 8 KiB
    __shared__ float hs[16][FH + 4];     // 8.25 KiB
    int tid = threadIdx.x;
    #pragma unroll
    for (int j = 0; j < (FH * FO) / 256; j++) {
        int i = tid + j * 256;
        w2s[i >> 4][i & 15] = W2[i];
    }

    int node0 = blockIdx.x * 16;
    int local = tid >> 4;
    int j = tid & 15;             // 16B unit: cols 8j..8j+7
    int node = node0 + local;

    if (node < N) {
        int beg = rd2[node].x, end = rd2[node + 1].x;
        const uint4* hp = (const uint4*)h1;

        float a[8];
        #pragma unroll
        for (int t = 0; t < 8; t++) a[t] = 0.f;

        int i = beg;
        for (; i + 8 <= end; i += 8) {
            int2 e[8];
            uint4 gg[8];
            #pragma unroll
            for (int t = 0; t < 8; t++) e[t] = ed[i + t];
            #pragma unroll
            for (int t = 0; t < 8; t++) gg[t] = hp[(size_t)e[t].x * 16 + j];
            #pragma unroll
            for (int t = 0; t < 8; t++) {
                float w = __int_as_float(e[t].y);
                #pragma unroll
                for (int q = 0; q < 4; q++) {
                    uint u = (&gg[t].x)[q];
                    a[q*2+0] += __uint_as_float(u << 16) * w;
                    a[q*2+1] += __uint_as_float(u & 0xFFFF0000u) * w;
                }
            }
        }
        for (; i + 4 <= end; i += 4) {
            int2 e0 = ed[i + 0], e1 = ed[i + 1], e2 = ed[i + 2], e3 = ed[i + 3];
            float w0 = __int_as_float(e0.y), w1 = __int_as_float(e1.y);
            float w2 = __int_as_float(e2.y), w3 = __int_as_float(e3.y);
            uint4 g0 = hp[(size_t)e0.x * 16 + j];
            uint4 g1 = hp[(size_t)e1.x * 16 + j];
            uint4 g2 = hp[(size_t)e2.x * 16 + j];
            uint4 g3 = hp[(size_t)e3.x * 16 + j];
            #pragma unroll
            for (int q = 0; q < 4; q++) {
                uint u0 = (&g0.x)[q], u1 = (&g1.x)[q], u2 = (&g2.x)[q], u3 = (&g3.x)[q];
                a[q*2+0] += __uint_as_float(u0 << 16) * w0;
                a[q*2+1] += __uint_as_float(u0 & 0xFFFF0000u) * w0;
                a[q*2+0] += __uint_as_float(u1 << 16) * w1;
                a[q*2+1] += __uint_as_float(u1 & 0xFFFF0000u) * w1;
                a[q*2+0] += __uint_as_float(u2 << 16) * w2;
                a[q*2+1] += __uint_as_float(u2 & 0xFFFF0000u) * w2;
                a[q*2+0] += __uint_as_float(u3 << 16) * w3;
                a[q*2+1] += __uint_as_float(u3 & 0xFFFF0000u) * w3;
            }
        }
        for (; i < end; i++) {
            int2 e = ed[i];
            float w = __int_as_float(e.y);
            uint4 g = hp[(size_t)e.x * 16 + j];
            #pragma unroll
            for (int q = 0; q < 4; q++) {
                uint u = (&g.x)[q];
                a[q*2+0] += __uint_as_float(u << 16) * w;
                a[q*2+1] += __uint_as_float(u & 0xFFFF0000u) * w;
            }
        }

        const float4* bp = (const float4*)b1;
        float4 bb0 = bp[j * 2 + 0];
        float4 bb1 = bp[j * 2 + 1];
        float4 o0, o1;
        o0.x = fmaxf(a[0] + bb0.x, 0.f);
        o0.y = fmaxf(a[1] + bb0.y, 0.f);
        o0.z = fmaxf(a[2] + bb0.z, 0.f);
        o0.w = fmaxf(a[3] + bb0.w, 0.f);
        o1.x = fmaxf(a[4] + bb1.x, 0.f);
        o1.y = fmaxf(a[5] + bb1.y, 0.f);
        o1.z = fmaxf(a[6] + bb1.z, 0.f);
        o1.w = fmaxf(a[7] + bb1.w, 0.f);
        *(float4*)&hs[local][j * 8 + 0] = o0;
        *(float4*)&hs[local][j * 8 + 4] = o1;
    }
    __syncthreads();

    float acc = 0.f;
    #pragma unroll 8
    for (int k = 0; k < FH; k++) acc += hs[local][k] * w2s[k][j];
    if (node < N) h2b[(size_t)node * FO + j] = f2bf(acc);
}

// AGG2 (bf16 h2) + bias + log_softmax. 8 lanes/node, 2 cols/lane, x8 unroll.
__global__ __launch_bounds__(256) void GCN_agg2_k(const ushort* __restrict__ h2b,
                                                  const int2* __restrict__ rd2,
                                                  const int2* __restrict__ ed,
                                                  const float* __restrict__ b2,
                                                  float* __restrict__ out, int N) {
    int tid = threadIdx.x;
    int node = blockIdx.x * 32 + (tid >> 3);
    if (node >= N) return;
    int f2 = tid & 7;                        // cols 2*f2, 2*f2+1
    int beg = rd2[node].x, end = rd2[node + 1].x;
    const uint* hp = (const uint*)h2b;       // row = 8 uints (16 bf16)
    float a0 = 0.f, a1 = 0.f;
    int i = beg;
    for (; i + 8 <= end; i += 8) {
        int2 e[8];
        uint u[8];
        #pragma unroll
        for (int t = 0; t < 8; t++) e[t] = ed[i + t];
        #pragma unroll
        for (int t = 0; t < 8; t++) u[t] = hp[(size_t)e[t].x * 8 + f2];
        #pragma unroll
        for (int t = 0; t < 8; t++) {
            float w = __int_as_float(e[t].y);
            a0 += __uint_as_float(u[t] << 16) * w;
            a1 += __uint_as_float(u[t] & 0xFFFF0000u) * w;
        }
    }
    for (; i + 4 <= end; i += 4) {
        int2 e0 = ed[i + 0], e1 = ed[i + 1], e2 = ed[i + 2], e3 = ed[i + 3];
        uint u0 = hp[(size_t)e0.x * 8 + f2];
        uint u1 = hp[(size_t)e1.x * 8 + f2];
        uint u2 = hp[(size_t)e2.x * 8 + f2];
        uint u3 = hp[(size_t)e3.x * 8 + f2];
        float w0 = __int_as_float(e0.y), w1 = __int_as_float(e1.y);
        float w2 = __int_as_float(e2.y), w3 = __int_as_float(e3.y);
        a0 += __uint_as_float(u0 << 16) * w0 + __uint_as_float(u1 << 16) * w1
            + __uint_as_float(u2 << 16) * w2 + __uint_as_float(u3 << 16) * w3;
        a1 += __uint_as_float(u0 & 0xFFFF0000u) * w0 + __uint_as_float(u1 & 0xFFFF0000u) * w1
            + __uint_as_float(u2 & 0xFFFF0000u) * w2 + __uint_as_float(u3 & 0xFFFF0000u) * w3;
    }
    for (; i < end; i++) {
        int2 e = ed[i];
        uint u = hp[(size_t)e.x * 8 + f2];
        float w = __int_as_float(e.y);
        a0 += __uint_as_float(u << 16) * w;
        a1 += __uint_as_float(u & 0xFFFF0000u) * w;
    }
    float2 bb = ((const float2*)b2)[f2];
    float v0 = a0 + bb.x;
    float v1 = a1 + bb.y;
    float mx = fmaxf(v0, v1);
    #pragma unroll
    for (int m = 4; m >= 1; m >>= 1) mx = fmaxf(mx, __shfl_xor(mx, m, 8));
    float s = expf(v0 - mx) + expf(v1 - mx);
    #pragma unroll
    for (int m = 4; m >= 1; m >>= 1) s += __shfl_xor(s, m, 8);
    float ls = logf(s);
    float2 o = make_float2(v0 - mx - ls, v1 - mx - ls);
    ((float2*)out)[(size_t)node * 8 + f2] = o;
}

extern "C" void kernel_launch(void* const* d_in, const int* in_sizes, int n_in,
                              void* d_out, int out_size, void* d_ws, size_t ws_size,
                              hipStream_t stream) {
    (void)n_in; (void)out_size; (void)ws_size;
    const float* x  = (const float*)d_in[0];
    const int*   edp = (const int*)d_in[1];
    const float* W1 = (const float*)d_in[2];
    const float* b1 = (const float*)d_in[3];
    const float* W2 = (const float*)d_in[4];
    const float* b2 = (const float*)d_in[5];
    float* out = (float*)d_out;

    int N = in_sizes[0] / FIN;   // 50000
    int E = in_sizes[1] / 2;     // 800000
    int M = E + N;
    int nWords = (N + 3) / 4;                // 12500 (4 nodes/word)
    int wph = (nWords + 1) / 2;              // 6250 (<= WPH)
    int nScanBlocks = (N + 255) / 256;       // 196
    int nChpfx = (nWords + 63) / 64;         // 196 (matches scan2 blocks)

    char* p = (char*)d_ws;
    auto take = [&](size_t bytes) -> char* {
        char* r = p;
        p += (bytes + 255) & ~(size_t)255;
        return r;
    };
    int*    count  = (int*)take((size_t)N * 4);
    int*    rank   = (int*)take((size_t)E * 4);
    uint*   cw     = (uint*)take((size_t)NCHUNK * nWords * 4);   // 4.9 MB
    int2*   rd2    = (int2*)take((size_t)(N + 1) * 8);
    int*    bsum   = (int*)take((size_t)nChpfx * 4);
    int2*   edata  = (int2*)take((size_t)M * 8);
    ushort* whT    = (ushort*)take((size_t)FH * FIN * 2);
    ushort* wlT    = (ushort*)take((size_t)FH * FIN * 2);
    ushort* h1     = (ushort*)take((size_t)N * FH * 2);
    ushort* h2b    = (ushort*)take((size_t)N * FO * 2);

    int eBlocks = (E + 255) / 256;            // 3125
    int nGemm   = (N + G1_BR - 1) / G1_BR;    // 782
    int nHist   = 2 * NCHUNK;                 // 196

    GCN_wprep_k<<<(FIN * FH) / 256, 256, 0, stream>>>(W1, whT, wlT);
    GCN_histgemm_k<<<nHist + nGemm, 256, 0, stream>>>(
        x, whT, wlT, h1, edp, cw, rank, N, E, nHist, nWords, wph);
    GCN_chpfx_k<<<nChpfx, 256, 0, stream>>>(cw, count, bsum, N, nWords);
    GCN_scan2_k<<<nScanBlocks, 256, 0, stream>>>(count, bsum, rd2, edata, N);
    GCN_fill_k<<<eBlocks, 256, 0, stream>>>(edp, rank, cw, rd2, edata, E, nWords);
    GCN_agg1gemm2_k<<<(N + 15) / 16, 256, 0, stream>>>(h1, rd2, edata, b1, W2, h2b, N);
    GCN_agg2_k<<<(N + 31) / 32, 256, 0, stream>>>(h2b, rd2, edata, b2, out, N);
}